// Round 5
// baseline (683.947 us; speedup 1.0000x reference)
//
#include <hip/hip_runtime.h>
#include <cstdint>
#include <cstddef>

#define B_ 4
#define T_ 2048
#define D_ 1024
#define H_ 16

typedef __attribute__((ext_vector_type(8))) short short8;     // 8 bf16 (4 VGPRs) for MFMA A/B frags
typedef __attribute__((ext_vector_type(4))) float f32x4;      // MFMA C/D frag
typedef __attribute__((ext_vector_type(8))) unsigned short u16x8;

__device__ __forceinline__ unsigned short f2b16(float f) {
  union { float f; unsigned int u; } un; un.f = f;
  unsigned int r = un.u + 0x7fffu + ((un.u >> 16) & 1u);  // round-to-nearest-even
  return (unsigned short)(r >> 16);
}
__device__ __forceinline__ void async_cp16(const void* g, void* l) {
  __builtin_amdgcn_global_load_lds((const __attribute__((address_space(1))) void*)g,
                                   (__attribute__((address_space(3))) void*)l,
                                   16, 0, 0);
}
__device__ __forceinline__ f32x4 mfma16(short8 a, short8 b, f32x4 c) {
  return __builtin_amdgcn_mfma_f32_16x16x32_bf16(a, b, c, 0, 0, 0);
}

// ====== prep: fused LayerNorm + transpose_cast(w_qkv) + transpose_cast(w_proj)
__global__ __launch_bounds__(256) void prep_kernel(const float* __restrict__ x,
                                                   const float* __restrict__ gamma,
                                                   const float* __restrict__ beta,
                                                   unsigned short* __restrict__ xn,
                                                   const float* __restrict__ wq,
                                                   unsigned short* __restrict__ wTq,
                                                   const float* __restrict__ wp,
                                                   unsigned short* __restrict__ wTp) {
  __shared__ float sh[8];
  __shared__ float tile[32][33];
  const int bid = blockIdx.x;
  const int t = threadIdx.x;

  if (bid < 8192) {
    const int row = bid;
    const float4 v = ((const float4*)(x + (size_t)row * D_))[t];
    float s  = v.x + v.y + v.z + v.w;
    float s2 = v.x*v.x + v.y*v.y + v.z*v.z + v.w*v.w;
    #pragma unroll
    for (int off = 32; off > 0; off >>= 1) {
      s  += __shfl_down(s, off);
      s2 += __shfl_down(s2, off);
    }
    const int wv = t >> 6, lane = t & 63;
    if (lane == 0) { sh[wv] = s; sh[4 + wv] = s2; }
    __syncthreads();
    if (t == 0) {
      float ts  = sh[0] + sh[1] + sh[2] + sh[3];
      float ts2 = sh[4] + sh[5] + sh[6] + sh[7];
      float mu  = ts * (1.0f / D_);
      float var = ts2 * (1.0f / D_) - mu * mu;
      sh[0] = mu;
      sh[1] = rsqrtf(var + 1e-5f);
    }
    __syncthreads();
    const float mu = sh[0], rs = sh[1];
    const float4 g  = ((const float4*)gamma)[t];
    const float4 bb = ((const float4*)beta)[t];
    ushort4 o;
    o.x = f2b16((v.x - mu) * rs * g.x + bb.x);
    o.y = f2b16((v.y - mu) * rs * g.y + bb.y);
    o.z = f2b16((v.z - mu) * rs * g.z + bb.z);
    o.w = f2b16((v.w - mu) * rs * g.w + bb.w);
    ((ushort4*)(xn + (size_t)row * D_))[t] = o;
  } else {
    const float* w; unsigned short* wT; int K, N, bx, by;
    if (bid < 8192 + 3072) {
      const int idx = bid - 8192;
      w = wq; wT = wTq; K = 1024; N = 3072; bx = idx % 96; by = idx / 96;
    } else {
      const int idx = bid - 11264;
      w = wp; wT = wTp; K = 1024; N = 1024; bx = idx % 32; by = idx / 32;
    }
    const int n0 = bx * 32, k0 = by * 32;
    const int tx = t & 31, ty = t >> 5;
    #pragma unroll
    for (int i = 0; i < 32; i += 8)
      tile[ty + i][tx] = w[(size_t)(k0 + ty + i) * N + n0 + tx];
    __syncthreads();
    #pragma unroll
    for (int i = 0; i < 32; i += 8)
      wT[(size_t)(n0 + ty + i) * K + k0 + tx] = f2b16(tile[tx][ty + i]);
  }
}

// ========= single-buffer GEMM, 2 blocks/CU (m97-regime at 256²) =========
// MODE 0: BM=BN=256, grid 384 (32Mx12N), LDS 64KB single-buffered ->
//   2 blocks/CU: ALL 384 blocks resident (no round-2 idle); the vmcnt(0)
//   staging drain of one block hides under the co-resident block's MFMA
//   burst (m97/m114 implicit-overlap regime). Per K-tile:
//   {barrier; 8x global_load_lds; __syncthreads; 64 MFMA (compiler lgkm)}.
//   Chunk-XOR swizzle (c^=row&7) -> conflict-free ds_read_b128.
//   Epilogue: Q/K per-wave LDS restage -> coalesced b128 stores;
//   V fused-transpose -> vtB in per-(qm,tb) passes (fits 64KB scratch).
// MODE 1: BM=BN=128, grid 512 (64Mx8N), LDS 32KB, 2 blocks/CU balanced;
//   fp32 out = acc + bias + resid.
// Accumulation order per element (ks0 then ks1) identical to R1-R4 ->
// bit-identical outputs.
template <int MODE, int NN>
__global__ __launch_bounds__(512, 4) void gemm_sb(const unsigned short* __restrict__ A,
                                                  const unsigned short* __restrict__ Bt,
                                                  const float* __restrict__ bias,
                                                  const float* __restrict__ resid,
                                                  unsigned short* __restrict__ qB,
                                                  unsigned short* __restrict__ kB,
                                                  unsigned short* __restrict__ vtB,
                                                  float* __restrict__ outF) {
  constexpr int K  = 1024;
  constexpr int NT = 16;                       // K / 64
  constexpr int BM = (MODE == 0) ? 256 : 128;  // = BN
  constexpr int FM = (MODE == 0) ? 2 : 1;      // row frags per (qm, wave)
  constexpr int FN = (MODE == 0) ? 4 : 2;      // col frags per (qn, wave)
  constexpr int ASH = BM * 64;                 // shorts per operand region
  __shared__ __align__(16) unsigned short S[2 * ASH];

  const int tid  = threadIdx.x;
  const int lane = tid & 63;
  const int wv   = tid >> 6;
  const int l15  = lane & 15, quad = lane >> 4;
  const int wr   = wv >> 1, wc = wv & 1;

  constexpr int MT  = 8192 / BM;               // M tiles
  constexpr int NTL = NN / BM;                 // N tiles
  constexpr int CPX = (MT * NTL) / 8;          // grid % 8 == 0 (bijective)
  const int w = (blockIdx.x & 7) * CPX + (blockIdx.x >> 3);
  const int tileM = (w % MT) * BM;
  const int tileN = (w / MT) * BM;

  // staging: cp-set = 64 rows x 128B; thread -> row tid>>3, pre-swizzled chunk
  const int sr  = tid >> 3;
  const int scs = ((tid & 7) ^ (sr & 7)) * 8;
  const unsigned short* gA = A  + (size_t)(tileM + sr) * K + scs;
  const unsigned short* gB = Bt + (size_t)(tileN + sr) * K + scs;

  const int rA = wr * (BM / 8) + l15;          // row within A qm-half
  const int rB = wc * (BM / 4) + l15;          // row within B qn-half

  f32x4 acc[2][2][FM][FN] = {};

  for (int kt = 0; kt < NT; ++kt) {
    if (kt) __syncthreads();                   // all reads of tile kt-1 done
    const int ko = kt * 64;
    #pragma unroll
    for (int p = 0; p < BM / 64; ++p) {
      async_cp16(gA + (size_t)(p * 64) * K + ko, &S[p * 4096 + tid * 8]);
      async_cp16(gB + (size_t)(p * 64) * K + ko, &S[ASH + p * 4096 + tid * 8]);
    }
    __syncthreads();                           // drains vmcnt(0): tile visible

    #pragma unroll
    for (int ks = 0; ks < 2; ++ks) {
      const int ck = (((ks << 2) | quad) ^ (l15 & 7)) * 8;
      short8 a[2 * FM];
      #pragma unroll
      for (int qm = 0; qm < 2; ++qm)
        #pragma unroll
        for (int fm = 0; fm < FM; ++fm)
          a[qm * FM + fm] = *(const short8*)&S[qm * (ASH / 2) + (rA + fm * 16) * 64 + ck];
      #pragma unroll
      for (int qn = 0; qn < 2; ++qn) {
        short8 b[FN];
        #pragma unroll
        for (int fn = 0; fn < FN; ++fn)
          b[fn] = *(const short8*)&S[ASH + qn * (ASH / 2) + (rB + fn * 16) * 64 + ck];
        __builtin_amdgcn_s_setprio(1);
        #pragma unroll
        for (int qm = 0; qm < 2; ++qm)
          #pragma unroll
          for (int fm = 0; fm < FM; ++fm)
            #pragma unroll
            for (int fn = 0; fn < FN; ++fn)
              acc[qm][qn][fm][fn] = mfma16(a[qm * FM + fm], b[fn], acc[qm][qn][fm][fn]);
        __builtin_amdgcn_s_setprio(0);
      }
    }
  }
  __syncthreads();   // all waves done reading S: epilogue may reuse it

  if constexpr (MODE == 1) {
    #pragma unroll
    for (int qm = 0; qm < 2; ++qm)
      #pragma unroll
      for (int qn = 0; qn < 2; ++qn)
        #pragma unroll
        for (int fn = 0; fn < FN; ++fn) {
          const int col = tileN + qn * 64 + wc * 32 + fn * 16 + l15;
          const float bv = bias[col];
          #pragma unroll
          for (int r = 0; r < 4; ++r) {
            const int row = tileM + qm * 64 + wr * 16 + quad * 4 + r;
            const size_t idx = (size_t)row * NN + col;
            outF[idx] = acc[qm][qn][0][fn][r] + bv + resid[idx];
          }
        }
  } else if (tileN < 2048) {
    // ---- Q/K epilogue: per-wave LDS restage -> coalesced b128 stores
    unsigned short* E = &S[wv * 2304];   // 32 x 72, wave-local (8*2304 <= 32768)
    #pragma unroll
    for (int qm = 0; qm < 2; ++qm) {
      #pragma unroll
      for (int qn = 0; qn < 2; ++qn) {
        const int colBase = tileN + qn * 128 + wc * 64;
        const int rowBase = tileM + qm * 128 + wr * 32;
        #pragma unroll
        for (int fn = 0; fn < 4; ++fn) {
          const int col = colBase + fn * 16 + l15;
          const float bv = bias[col];
          const float sc = (col < 1024) ? 0.180336880f : 1.0f;  // Q: fold 0.125*log2e
          #pragma unroll
          for (int fm = 0; fm < 2; ++fm)
            #pragma unroll
            for (int r = 0; r < 4; ++r)
              E[(fm * 16 + quad * 4 + r) * 72 + fn * 16 + l15] =
                  f2b16((acc[qm][qn][fm][fn][r] + bv) * sc);
        }
        const int secq = colBase >> 10;                    // 0=Q, 1=K
        const int hh   = (colBase & 1023) >> 6;
        unsigned short* outSec = (secq == 0) ? qB : kB;
        #pragma unroll
        for (int it = 0; it < 4; ++it) {
          const int lrow = it * 8 + (lane >> 3);
          const int row = rowBase + lrow;
          const int b_ = row >> 11, tt = row & 2047;
          const u16x8 val = *(const u16x8*)&E[lrow * 72 + (lane & 7) * 8];
          *(u16x8*)(outSec + ((size_t)(b_ * 16 + hh) * T_ + tt) * 64 + (lane & 7) * 8) = val;
        }
      }
    }
  } else {
    // ---- V epilogue: fused transpose -> vtB[bh][dv][t'] (c' permuted).
    // Per-(qm, tb) passes: 4 head-tiles [64 dv][72] = 18432 shorts <= 32768.
    // c'(u) = 32*(wr&1) + 8*quad + 4*fm + r  (inverse of attn's t(c) map);
    // wave's rows belong to tb = wr>>1 within the qm-half.
    const int b_    = tileM >> 11;
    const int tbase = tileM & 2047;
    const int h0    = (tileN - 2048) >> 6;
    const int myTb  = wr >> 1;
    const int cpr   = 32 * (wr & 1) + 8 * quad;
    #pragma unroll
    for (int qm = 0; qm < 2; ++qm) {
      #pragma unroll
      for (int tb = 0; tb < 2; ++tb) {
        if (myTb == tb) {
          #pragma unroll
          for (int qn = 0; qn < 2; ++qn) {
            const int head = qn * 2 + wc;
            const int colBase = tileN + qn * 128 + wc * 64;
            #pragma unroll
            for (int fn = 0; fn < 4; ++fn) {
              const int dv = fn * 16 + l15;
              const float bv = bias[colBase + fn * 16 + l15];
              #pragma unroll
              for (int fm = 0; fm < 2; ++fm)
                #pragma unroll
                for (int r = 0; r < 4; ++r)
                  S[head * 4608 + dv * 72 + cpr + 4 * fm + r] =
                      f2b16(acc[qm][qn][fm][fn][r] + bv);
            }
          }
        }
        __syncthreads();
        {
          const int head = wv & 3;
          const int dvh  = wv >> 2;
          const size_t base = ((size_t)(b_ * 16 + h0 + head) * 64) * T_ +
                              tbase + qm * 128 + tb * 64;
          const int c4 = (lane & 15) * 4;
          #pragma unroll
          for (int i = 0; i < 8; ++i) {
            const int dv = dvh * 32 + i * 4 + (lane >> 4);
            const ushort4 val = *(const ushort4*)&S[head * 4608 + dv * 72 + c4];
            *(ushort4*)(vtB + base + (size_t)dv * T_ + c4) = val;
          }
        }
        __syncthreads();
      }
    }
  }
}

// ---------------- MFMA flash attention v8 (+T5 setprio) -----------------
__global__ __launch_bounds__(256, 4) void attn_mfma(const unsigned short* __restrict__ qB,
                                                    const unsigned short* __restrict__ kB,
                                                    const unsigned short* __restrict__ vtB,
                                                    unsigned short* __restrict__ aout) {
  __shared__ unsigned short Ks[2][64 * 64];
  __shared__ unsigned short Vs[2][64 * 64];

  const int tid = threadIdx.x;
  const int bid = blockIdx.x;
  const int bh = bid & 63;
  const int qb = bid >> 6;
  const int b = bh >> 4, h = bh & 15;
  const int wv = tid >> 6, lane = tid & 63;
  const int l15 = lane & 15, quad = lane >> 4;

  const unsigned short* qP = qB  + (size_t)bh * T_ * 64;
  const unsigned short* kP = kB  + (size_t)bh * T_ * 64;
  const unsigned short* vP = vtB + (size_t)bh * 64 * T_;
  const int q0 = qb * 128 + wv * 32;

  short8 qf[2][2];
  #pragma unroll
  for (int mi = 0; mi < 2; ++mi)
    #pragma unroll
    for (int ks = 0; ks < 2; ++ks)
      qf[mi][ks] = *(const short8*)(qP + ((size_t)(q0 + mi * 16 + l15)) * 64 + ks * 32 + quad * 8);

  const short8 onesf = {0x3F80, 0x3F80, 0x3F80, 0x3F80, 0x3F80, 0x3F80, 0x3F80, 0x3F80};
  f32x4 accO[2][5] = {};

  const int lrow  = lane >> 3;
  const int lchnk = (lane & 7) ^ (lrow & 7);
  const size_t kOff0 = (size_t)((wv * 2 + 0) * 8 + lrow) * 64 + lchnk * 8;
  const size_t kOff1 = (size_t)((wv * 2 + 1) * 8 + lrow) * 64 + lchnk * 8;
  const size_t vOff0 = (size_t)((wv * 2 + 0) * 8 + lrow) * T_ + lchnk * 8;
  const size_t vOff1 = (size_t)((wv * 2 + 1) * 8 + lrow) * T_ + lchnk * 8;
  const int lOff0 = (wv * 2 + 0) * 512 + lane * 8;
  const int lOff1 = (wv * 2 + 1) * 512 + lane * 8;

  async_cp16(kP + kOff0, &Ks[0][lOff0]);
  async_cp16(kP + kOff1, &Ks[0][lOff1]);
  async_cp16(vP + vOff0, &Vs[0][lOff0]);
  async_cp16(vP + vOff1, &Vs[0][lOff1]);
  __syncthreads();

  for (int kt = 0; kt < 32; ++kt) {
    const int buf = kt & 1;
    if (kt + 1 < 32) {
      const unsigned short* kg = kP + (size_t)(kt + 1) * 64 * 64;
      const unsigned short* vg = vP + (kt + 1) * 64;
      async_cp16(kg + kOff0, &Ks[buf ^ 1][lOff0]);
      async_cp16(kg + kOff1, &Ks[buf ^ 1][lOff1]);
      async_cp16(vg + vOff0, &Vs[buf ^ 1][lOff0]);
      async_cp16(vg + vOff1, &Vs[buf ^ 1][lOff1]);
    }
    const unsigned short* K_ = Ks[buf];
    const unsigned short* V_ = Vs[buf];

    f32x4 accT[4][2] = {};
    __builtin_amdgcn_s_setprio(1);
    #pragma unroll
    for (int ks = 0; ks < 2; ++ks) {
      #pragma unroll
      for (int cc = 0; cc < 4; ++cc) {
        const short8 kb = *(const short8*)&K_[(cc * 16 + l15) * 64 +
                                              (((ks << 2) | quad) ^ (l15 & 7)) * 8];
        accT[cc][0] = mfma16(kb, qf[0][ks], accT[cc][0]);
        accT[cc][1] = mfma16(kb, qf[1][ks], accT[cc][1]);
      }
    }
    __builtin_amdgcn_s_setprio(0);

    short8 pa[2][2];
    #pragma unroll
    for (int mi = 0; mi < 2; ++mi) {
      #pragma unroll
      for (int ks = 0; ks < 2; ++ks) {
        union { unsigned short u[8]; short8 s; } pk;
        #pragma unroll
        for (int r = 0; r < 4; ++r) {
          union { float f; unsigned int u; } e0, e1;
          e0.f = __builtin_amdgcn_exp2f(accT[2 * ks + 0][mi][r]);
          e1.f = __builtin_amdgcn_exp2f(accT[2 * ks + 1][mi][r]);
          pk.u[r]     = (unsigned short)(e0.u >> 16);
          pk.u[4 + r] = (unsigned short)(e1.u >> 16);
        }
        pa[mi][ks] = pk.s;
      }
    }

    __builtin_amdgcn_s_setprio(1);
    #pragma unroll
    for (int ks = 0; ks < 2; ++ks) {
      short8 vb[4];
      #pragma unroll
      for (int nj = 0; nj < 4; ++nj)
        vb[nj] = *(const short8*)&V_[(nj * 16 + l15) * 64 +
                                     (((ks << 2) | quad) ^ (l15 & 7)) * 8];
      #pragma unroll
      for (int mi = 0; mi < 2; ++mi) {
        #pragma unroll
        for (int nj = 0; nj < 4; ++nj)
          accO[mi][nj] = mfma16(pa[mi][ks], vb[nj], accO[mi][nj]);
        accO[mi][4] = mfma16(pa[mi][ks], onesf, accO[mi][4]);
      }
    }
    __builtin_amdgcn_s_setprio(0);

    __syncthreads();
  }

  #pragma unroll
  for (int mi = 0; mi < 2; ++mi) {
    #pragma unroll
    for (int r = 0; r < 4; ++r) {
      const float inv = 1.0f / accO[mi][4][r];
      const int row = q0 + mi * 16 + quad * 4 + r;
      unsigned short* op = aout + (size_t)(b * T_ + row) * D_ + h * 64 + l15;
      #pragma unroll
      for (int nj = 0; nj < 4; ++nj)
        op[nj * 16] = f2b16(accO[mi][nj][r] * inv);
    }
  }
}

extern "C" void kernel_launch(void* const* d_in, const int* in_sizes, int n_in,
                              void* d_out, int out_size, void* d_ws, size_t ws_size,
                              hipStream_t stream) {
  const float* x      = (const float*)d_in[0];
  const float* w_qkv  = (const float*)d_in[1];
  const float* b_qkv  = (const float*)d_in[2];
  const float* w_proj = (const float*)d_in[3];
  const float* b_proj = (const float*)d_in[4];
  const float* ln_g   = (const float*)d_in[5];
  const float* ln_b   = (const float*)d_in[6];
  float* out = (float*)d_out;

  char* ws = (char*)d_ws;
  unsigned short* xn   = (unsigned short*)(ws);                       // 16 MB (reused as aout)
  unsigned short* wTq  = (unsigned short*)(ws + (size_t)(16 << 20));  //  6 MB
  unsigned short* wTp  = (unsigned short*)(ws + (size_t)(22 << 20));  //  2 MB
  unsigned short* qBuf = (unsigned short*)(ws + (size_t)(24 << 20));  // 16 MB
  unsigned short* kBuf = (unsigned short*)(ws + (size_t)(40 << 20));  // 16 MB
  unsigned short* vtB  = (unsigned short*)(ws + (size_t)(72 << 20));  // 16 MB
  unsigned short* aout = xn;   // xn is dead after QKV gemm; attn reuses it

  // 1. fused prep: LN + both weight transposes (one dispatch)
  prep_kernel<<<12288, 256, 0, stream>>>(x, ln_g, ln_b, xn, w_qkv, wTq, w_proj, wTp);
  // 2. QKV projection: 256^2 single-buffer, 2 blocks/CU, fused V-transpose
  gemm_sb<0, 3072><<<384, 512, 0, stream>>>(xn, wTq, b_qkv, nullptr,
                                            qBuf, kBuf, vtB, nullptr);
  // 3. MFMA flash attention v8 (+setprio)
  attn_mfma<<<1024, 256, 0, stream>>>(qBuf, kBuf, vtB, aout);
  // 4. output projection: 128^2 single-buffer, grid 512 = 2/CU balanced
  gemm_sb<1, 1024><<<512, 512, 0, stream>>>(aout, wTp, b_proj, x,
                                            nullptr, nullptr, nullptr, out);
}

// Round 6
// 267.857 us; speedup vs baseline: 2.5534x; 2.5534x over previous
//
#include <hip/hip_runtime.h>
#include <cstdint>
#include <cstddef>

#define B_ 4
#define T_ 2048
#define D_ 1024
#define H_ 16

typedef __attribute__((ext_vector_type(8))) short short8;     // 8 bf16 (4 VGPRs) for MFMA A/B frags
typedef __attribute__((ext_vector_type(4))) float f32x4;      // MFMA C/D frag
typedef __attribute__((ext_vector_type(8))) unsigned short u16x8;

__device__ __forceinline__ unsigned short f2b16(float f) {
  union { float f; unsigned int u; } un; un.f = f;
  unsigned int r = un.u + 0x7fffu + ((un.u >> 16) & 1u);  // round-to-nearest-even
  return (unsigned short)(r >> 16);
}
__device__ __forceinline__ void async_cp16(const void* g, void* l) {
  __builtin_amdgcn_global_load_lds((const __attribute__((address_space(1))) void*)g,
                                   (__attribute__((address_space(3))) void*)l,
                                   16, 0, 0);
}
__device__ __forceinline__ f32x4 mfma16(short8 a, short8 b, f32x4 c) {
  return __builtin_amdgcn_mfma_f32_16x16x32_bf16(a, b, c, 0, 0, 0);
}

// ====== prep: fused LayerNorm + transpose_cast(w_qkv) + transpose_cast(w_proj)
// One dispatch replaces three. Blocks:
//   [0, 8192)        : LN row  (fp32 -> bf16 normalized)
//   [8192, 11264)    : w_qkv transpose 96x32 tiles
//   [11264, 12288)   : w_proj transpose 32x32 tiles
__global__ __launch_bounds__(256) void prep_kernel(const float* __restrict__ x,
                                                   const float* __restrict__ gamma,
                                                   const float* __restrict__ beta,
                                                   unsigned short* __restrict__ xn,
                                                   const float* __restrict__ wq,
                                                   unsigned short* __restrict__ wTq,
                                                   const float* __restrict__ wp,
                                                   unsigned short* __restrict__ wTp) {
  __shared__ float sh[8];
  __shared__ float tile[32][33];
  const int bid = blockIdx.x;
  const int t = threadIdx.x;

  if (bid < 8192) {
    // ---- LayerNorm ----
    const int row = bid;
    const float4 v = ((const float4*)(x + (size_t)row * D_))[t];
    float s  = v.x + v.y + v.z + v.w;
    float s2 = v.x*v.x + v.y*v.y + v.z*v.z + v.w*v.w;
    #pragma unroll
    for (int off = 32; off > 0; off >>= 1) {
      s  += __shfl_down(s, off);
      s2 += __shfl_down(s2, off);
    }
    const int wv = t >> 6, lane = t & 63;
    if (lane == 0) { sh[wv] = s; sh[4 + wv] = s2; }
    __syncthreads();
    if (t == 0) {
      float ts  = sh[0] + sh[1] + sh[2] + sh[3];
      float ts2 = sh[4] + sh[5] + sh[6] + sh[7];
      float mu  = ts * (1.0f / D_);
      float var = ts2 * (1.0f / D_) - mu * mu;
      sh[0] = mu;
      sh[1] = rsqrtf(var + 1e-5f);
    }
    __syncthreads();
    const float mu = sh[0], rs = sh[1];
    const float4 g  = ((const float4*)gamma)[t];
    const float4 bb = ((const float4*)beta)[t];
    ushort4 o;
    o.x = f2b16((v.x - mu) * rs * g.x + bb.x);
    o.y = f2b16((v.y - mu) * rs * g.y + bb.y);
    o.z = f2b16((v.z - mu) * rs * g.z + bb.z);
    o.w = f2b16((v.w - mu) * rs * g.w + bb.w);
    ((ushort4*)(xn + (size_t)row * D_))[t] = o;
  } else {
    // ---- transpose + cast ----
    const float* w; unsigned short* wT; int K, N, bx, by;
    if (bid < 8192 + 3072) {
      const int idx = bid - 8192;
      w = wq; wT = wTq; K = 1024; N = 3072; bx = idx % 96; by = idx / 96;
    } else {
      const int idx = bid - 11264;
      w = wp; wT = wTp; K = 1024; N = 1024; bx = idx % 32; by = idx / 32;
    }
    const int n0 = bx * 32, k0 = by * 32;
    const int tx = t & 31, ty = t >> 5;
    #pragma unroll
    for (int i = 0; i < 32; i += 8)
      tile[ty + i][tx] = w[(size_t)(k0 + ty + i) * N + n0 + tx];
    __syncthreads();
    #pragma unroll
    for (int i = 0; i < 32; i += 8)
      wT[(size_t)(n0 + ty + i) * K + k0 + tx] = f2b16(tile[tx][ty + i]);
  }
}

// ============ 256x256 8-phase QKV GEMM (proven R1/R2/R4 schedule) =======
// BM=BN=256, BK=64, 512 threads = 8 waves (4M x 2N). Per-phase 16 MFMA,
// counted vmcnt fences (4/4/-/4), 1 barrier/phase. Grid 384 (32M x 12N).
// launch_bounds(512,2): 256-VGPR cap — REQUIRED. R5 proved (512,4)'s
// 128-VGPR cap spills the whole accumulator to scratch (VGPR=64, 2.2 GB
// HBM traffic, MfmaUtil 4%). 256^2 needs ~220 VGPRs; 1 block/CU it is.
// Epilogue: Q/K blocks: per-wave LDS restage -> coalesced b128 stores.
// V blocks (tileN >= 2048): fused V^T -> vtB[bh][dv][t'] (c' permuted),
// cross-wave LDS transpose tiles in dead As/Bs.
__global__ __launch_bounds__(512, 2) void gemm256_qkv(const unsigned short* __restrict__ A,
                                                      const unsigned short* __restrict__ Bt,
                                                      const float* __restrict__ bias,
                                                      unsigned short* __restrict__ qB,
                                                      unsigned short* __restrict__ kB,
                                                      unsigned short* __restrict__ vtB) {
  constexpr int K = 1024;
  constexpr int NT = K / 64;            // 16 K-tiles
  __shared__ __align__(16) unsigned short As[32768];   // 64KB: [buf][half][128][64]
  __shared__ __align__(16) unsigned short Bs[32768];   // 64KB

  const int tid  = threadIdx.x;
  const int lane = tid & 63;
  const int wv   = tid >> 6;            // 0..7
  const int l15  = lane & 15, quad = lane >> 4;
  const int wr   = wv >> 1;             // 0..3  (32-row slice within each qm-half)
  const int wc   = wv & 1;              // 0..1  (64-col slice within each qn-half)

  // XCD-bijective swizzle: 384 blocks, 48 per XCD chunk
  const int w = (blockIdx.x & 7) * 48 + (blockIdx.x >> 3);
  const int tileM = (w & 31) * 256;     // 32 M-tiles
  const int tileN = (w >> 5) * 256;     // 12 N-tiles

  const int sr  = tid >> 3;
  const int scs = ((tid & 7) ^ (sr & 7)) * 8;
  const unsigned short* gA = A  + (size_t)(tileM + sr) * K + scs;
  const unsigned short* gB = Bt + (size_t)(tileN + sr) * K + scs;

  auto stageA = [&](int h, int ko, int wbuf) {
    const unsigned short* g = gA + (size_t)(h * 128) * K + ko;
    unsigned short* l = &As[wbuf * 16384 + h * 8192 + tid * 8];
    async_cp16(g, l);
    async_cp16(g + (size_t)64 * K, l + 4096);
  };
  auto stageB = [&](int h, int ko, int wbuf) {
    const unsigned short* g = gB + (size_t)(h * 128) * K + ko;
    unsigned short* l = &Bs[wbuf * 16384 + h * 8192 + tid * 8];
    async_cp16(g, l);
    async_cp16(g + (size_t)64 * K, l + 4096);
  };

  const int rA  = wr * 32 + l15;
  const int rB  = wc * 64 + l15;
  const int ck0 = ((0 + quad) ^ (l15 & 7)) * 8;
  const int ck1 = ((4 + quad) ^ (l15 & 7)) * 8;

  f32x4 acc[2][2][2][4] = {};                     // [qm][qn][fm][fn]

#define MFMA16(QM, QN, AF, BF)                                                          \
  do {                                                                                  \
    _Pragma("unroll") for (int fm = 0; fm < 2; ++fm)                                    \
    _Pragma("unroll") for (int fn = 0; fn < 4; ++fn) {                                  \
      acc[QM][QN][fm][fn] = mfma16(AF[fm][0], BF[fn][0], acc[QM][QN][fm][fn]);          \
      acc[QM][QN][fm][fn] = mfma16(AF[fm][1], BF[fn][1], acc[QM][QN][fm][fn]);          \
    }                                                                                   \
  } while (0)

  stageA(0, 0, 0);
  stageB(0, 0, 0);
  stageB(1, 0, 0);
  stageA(1, 0, 0);
  asm volatile("s_waitcnt vmcnt(4)" ::: "memory");
  asm volatile("s_barrier" ::: "memory");

  #pragma unroll 2
  for (int kt = 0; kt < NT; ++kt) {
    const int buf = kt & 1;
    const unsigned short* Ab = &As[buf * 16384];
    const unsigned short* Bb = &Bs[buf * 16384];
    const int wbuf = buf ^ 1;
    const bool st = (kt + 1) < NT;
    const int ko = (kt + 1) * 64;

    short8 a[2][2], b0[4][2], b1[4][2];

    // ---- phase 0: quadrant (0,0); reads A-half0 + B-half0
    #pragma unroll
    for (int fm = 0; fm < 2; ++fm) {
      a[fm][0] = *(const short8*)&Ab[(rA + fm * 16) * 64 + ck0];
      a[fm][1] = *(const short8*)&Ab[(rA + fm * 16) * 64 + ck1];
    }
    #pragma unroll
    for (int fn = 0; fn < 4; ++fn) {
      b0[fn][0] = *(const short8*)&Bb[(rB + fn * 16) * 64 + ck0];
      b0[fn][1] = *(const short8*)&Bb[(rB + fn * 16) * 64 + ck1];
    }
    if (st) stageA(0, ko, wbuf);
    asm volatile("s_waitcnt lgkmcnt(0)" ::: "memory");
    __builtin_amdgcn_sched_barrier(0);
    __builtin_amdgcn_s_setprio(1);
    MFMA16(0, 0, a, b0);
    __builtin_amdgcn_s_setprio(0);
    if (st) asm volatile("s_waitcnt vmcnt(4)" ::: "memory");   // force Bh1(kt)
    else    asm volatile("s_waitcnt vmcnt(2)" ::: "memory");
    asm volatile("s_barrier" ::: "memory");

    // ---- phase 1: quadrant (0,1); reads B-half1
    #pragma unroll
    for (int fn = 0; fn < 4; ++fn) {
      b1[fn][0] = *(const short8*)&Bb[8192 + (rB + fn * 16) * 64 + ck0];
      b1[fn][1] = *(const short8*)&Bb[8192 + (rB + fn * 16) * 64 + ck1];
    }
    if (st) stageB(0, ko, wbuf);
    asm volatile("s_waitcnt lgkmcnt(0)" ::: "memory");
    __builtin_amdgcn_sched_barrier(0);
    __builtin_amdgcn_s_setprio(1);
    MFMA16(0, 1, a, b1);
    __builtin_amdgcn_s_setprio(0);
    if (st) asm volatile("s_waitcnt vmcnt(4)" ::: "memory");   // force Ah1(kt)
    else    asm volatile("s_waitcnt vmcnt(0)" ::: "memory");
    asm volatile("s_barrier" ::: "memory");

    // ---- phase 2: quadrant (1,0); reads A-half1
    #pragma unroll
    for (int fm = 0; fm < 2; ++fm) {
      a[fm][0] = *(const short8*)&Ab[8192 + (rA + fm * 16) * 64 + ck0];
      a[fm][1] = *(const short8*)&Ab[8192 + (rA + fm * 16) * 64 + ck1];
    }
    if (st) stageB(1, ko, wbuf);
    asm volatile("s_waitcnt lgkmcnt(0)" ::: "memory");
    __builtin_amdgcn_sched_barrier(0);
    __builtin_amdgcn_s_setprio(1);
    MFMA16(1, 0, a, b0);
    __builtin_amdgcn_s_setprio(0);
    asm volatile("s_barrier" ::: "memory");

    // ---- phase 3: quadrant (1,1); no ds_reads
    if (st) stageA(1, ko, wbuf);
    __builtin_amdgcn_s_setprio(1);
    MFMA16(1, 1, a, b1);
    __builtin_amdgcn_s_setprio(0);
    if (st) asm volatile("s_waitcnt vmcnt(4)" ::: "memory");   // force Ah0+Bh0(kt+1)
    asm volatile("s_barrier" ::: "memory");
  }
#undef MFMA16

  if (tileN < 2048) {
    // ---- Q/K epilogue: per-wave LDS restage -> coalesced b128 stores
    unsigned short* E = &As[wv * 2304];   // 32 x 72, wave-local
    #pragma unroll
    for (int qm = 0; qm < 2; ++qm) {
      #pragma unroll
      for (int qn = 0; qn < 2; ++qn) {
        const int colBase = tileN + qn * 128 + wc * 64;
        const int rowBase = tileM + qm * 128 + wr * 32;
        #pragma unroll
        for (int fn = 0; fn < 4; ++fn) {
          const int col = colBase + fn * 16 + l15;
          const float bv = bias[col];
          const float sc = (col < 1024) ? 0.180336880f : 1.0f;  // Q: fold 0.125*log2e
          #pragma unroll
          for (int fm = 0; fm < 2; ++fm)
            #pragma unroll
            for (int r = 0; r < 4; ++r)
              E[(fm * 16 + quad * 4 + r) * 72 + fn * 16 + l15] =
                  f2b16((acc[qm][qn][fm][fn][r] + bv) * sc);
        }
        const int secq = colBase >> 10;                    // 0=Q, 1=K
        const int hh   = (colBase & 1023) >> 6;
        unsigned short* outSec = (secq == 0) ? qB : kB;
        #pragma unroll
        for (int it = 0; it < 4; ++it) {
          const int lrow = it * 8 + (lane >> 3);
          const int row = rowBase + lrow;
          const int b_ = row >> 11, tt = row & 2047;
          const u16x8 val = *(const u16x8*)&E[lrow * 72 + (lane & 7) * 8];
          *(u16x8*)(outSec + ((size_t)(b_ * 16 + hh) * T_ + tt) * 64 + (lane & 7) * 8) = val;
        }
      }
    }
  } else {
    // ---- V epilogue: fused transpose -> vtB[bh][dv][t'] (c' permuted).
    // c'(u) = 32*(wr&1) + 8*quad + 4*fm + r  (inverse of attn's t(c) map).
    const int b_    = tileM >> 11;
    const int tbase = tileM & 2047;
    const int h0    = (tileN - 2048) >> 6;
    unsigned short* TL = (wr < 2) ? As : Bs;  // write-side tile array
    const int cpr = 32 * (wr & 1) + 8 * quad;
    #pragma unroll
    for (int qm = 0; qm < 2; ++qm) {
      // write phase
      #pragma unroll
      for (int qn = 0; qn < 2; ++qn) {
        const int head = qn * 2 + wc;
        const int colBase = tileN + qn * 128 + wc * 64;
        #pragma unroll
        for (int fn = 0; fn < 4; ++fn) {
          const int dv = fn * 16 + l15;
          const float bv = bias[colBase + fn * 16 + l15];
          #pragma unroll
          for (int fm = 0; fm < 2; ++fm)
            #pragma unroll
            for (int r = 0; r < 4; ++r)
              TL[head * 4352 + dv * 68 + cpr + 4 * fm + r] =
                  f2b16(acc[qm][qn][fm][fn][r] + bv);
        }
      }
      __syncthreads();
      // store phase: wave wv -> tile (tb = qm*2 + (wv>>2), head = wv&3)
      {
        const unsigned short* SA = (wv < 4) ? As : Bs;
        const int head = wv & 3;
        const int tb   = qm * 2 + (wv >> 2);
        const size_t base = ((size_t)(b_ * 16 + h0 + head) * 64) * T_ + tbase + tb * 64;
        const int c4 = (lane & 15) * 4;
        #pragma unroll
        for (int i = 0; i < 16; ++i) {
          const int dv = i * 4 + (lane >> 4);
          const ushort4 val = *(const ushort4*)&SA[head * 4352 + dv * 68 + c4];
          *(ushort4*)(vtB + base + (size_t)dv * T_ + c4) = val;
        }
      }
      __syncthreads();
    }
  }
}

// ------ 128x256 8-phase GEMM (output projection, fp32 + bias + resid) ---
template <int MODE, int NN>
__global__ __launch_bounds__(512, 2) void gemm8p(const unsigned short* __restrict__ A,
                                                 const unsigned short* __restrict__ Bt,
                                                 const float* __restrict__ bias,
                                                 const float* __restrict__ resid,
                                                 float* __restrict__ outF) {
  constexpr int K = 1024;
  constexpr int NT = 16;
  __shared__ __align__(16) unsigned short As[16384];
  __shared__ __align__(16) unsigned short Bs[32768];

  const int tid  = threadIdx.x;
  const int lane = tid & 63;
  const int wv   = tid >> 6;
  const int l15  = lane & 15, quad = lane >> 4;
  const int wr   = wv >> 1;
  const int wc   = wv & 1;

  constexpr int CPX = (64 * (NN / 256)) / 8;
  const int w = (blockIdx.x & 7) * CPX + (blockIdx.x >> 3);
  const int tileM = (w & 63) * 128;
  const int tileN = (w >> 6) * 256;

  const int sr  = tid >> 3;
  const int scs = ((tid & 7) ^ (sr & 7)) * 8;
  const unsigned short* gA = A  + (size_t)(tileM + sr) * K + scs;
  const unsigned short* gB = Bt + (size_t)(tileN + sr) * K + scs;

  auto stA = [&](int h, int ko, int wb) {
    async_cp16(gA + (size_t)(h * 64) * K + ko, &As[wb * 8192 + h * 4096 + tid * 8]);
  };
  auto stB = [&](int h, int ko, int wb) {
    const unsigned short* g = gB + (size_t)(h * 128) * K + ko;
    unsigned short* l = &Bs[wb * 16384 + h * 8192 + tid * 8];
    async_cp16(g, l);
    async_cp16(g + (size_t)64 * K, l + 4096);
  };

  const int rA  = wr * 16 + l15;
  const int rB  = wc * 64 + l15;
  const int ck0 = ((0 + quad) ^ (l15 & 7)) * 8;
  const int ck1 = ((4 + quad) ^ (l15 & 7)) * 8;

  f32x4 acc[2][2][4] = {};

  stA(0, 0, 0); stB(0, 0, 0); stB(1, 0, 0); stA(1, 0, 0);
  asm volatile("s_waitcnt vmcnt(3)" ::: "memory");
  asm volatile("s_barrier" ::: "memory");

  #pragma unroll 2
  for (int kt = 0; kt < NT; ++kt) {
    const int buf = kt & 1;
    const unsigned short* Ab = &As[buf * 8192];
    const unsigned short* Bb = &Bs[buf * 16384];
    const int wb = buf ^ 1;
    const bool st = (kt + 1) < NT;
    const int ko = (kt + 1) * 64;

    short8 a[2], b0[4][2], b1[4][2];

    a[0] = *(const short8*)&Ab[rA * 64 + ck0];
    a[1] = *(const short8*)&Ab[rA * 64 + ck1];
    #pragma unroll
    for (int fn = 0; fn < 4; ++fn) {
      b0[fn][0] = *(const short8*)&Bb[(rB + fn * 16) * 64 + ck0];
      b0[fn][1] = *(const short8*)&Bb[(rB + fn * 16) * 64 + ck1];
    }
    if (st) stA(0, ko, wb);
    asm volatile("s_waitcnt lgkmcnt(0)" ::: "memory");
    __builtin_amdgcn_sched_barrier(0);
    __builtin_amdgcn_s_setprio(1);
    #pragma unroll
    for (int fn = 0; fn < 4; ++fn) {
      acc[0][0][fn] = mfma16(a[0], b0[fn][0], acc[0][0][fn]);
      acc[0][0][fn] = mfma16(a[1], b0[fn][1], acc[0][0][fn]);
    }
    __builtin_amdgcn_s_setprio(0);
    if (st) asm volatile("s_waitcnt vmcnt(2)" ::: "memory");
    else    asm volatile("s_waitcnt vmcnt(1)" ::: "memory");
    asm volatile("s_barrier" ::: "memory");

    #pragma unroll
    for (int fn = 0; fn < 4; ++fn) {
      b1[fn][0] = *(const short8*)&Bb[8192 + (rB + fn * 16) * 64 + ck0];
      b1[fn][1] = *(const short8*)&Bb[8192 + (rB + fn * 16) * 64 + ck1];
    }
    if (st) stB(0, ko, wb);
    asm volatile("s_waitcnt lgkmcnt(0)" ::: "memory");
    __builtin_amdgcn_sched_barrier(0);
    __builtin_amdgcn_s_setprio(1);
    #pragma unroll
    for (int fn = 0; fn < 4; ++fn) {
      acc[0][1][fn] = mfma16(a[0], b1[fn][0], acc[0][1][fn]);
      acc[0][1][fn] = mfma16(a[1], b1[fn][1], acc[0][1][fn]);
    }
    __builtin_amdgcn_s_setprio(0);
    if (st) asm volatile("s_waitcnt vmcnt(3)" ::: "memory");
    else    asm volatile("s_waitcnt vmcnt(0)" ::: "memory");
    asm volatile("s_barrier" ::: "memory");

    a[0] = *(const short8*)&Ab[4096 + rA * 64 + ck0];
    a[1] = *(const short8*)&Ab[4096 + rA * 64 + ck1];
    if (st) stB(1, ko, wb);
    asm volatile("s_waitcnt lgkmcnt(0)" ::: "memory");
    __builtin_amdgcn_sched_barrier(0);
    __builtin_amdgcn_s_setprio(1);
    #pragma unroll
    for (int fn = 0; fn < 4; ++fn) {
      acc[1][0][fn] = mfma16(a[0], b0[fn][0], acc[1][0][fn]);
      acc[1][0][fn] = mfma16(a[1], b0[fn][1], acc[1][0][fn]);
    }
    __builtin_amdgcn_s_setprio(0);
    asm volatile("s_barrier" ::: "memory");

    if (st) stA(1, ko, wb);
    __builtin_amdgcn_s_setprio(1);
    #pragma unroll
    for (int fn = 0; fn < 4; ++fn) {
      acc[1][1][fn] = mfma16(a[0], b1[fn][0], acc[1][1][fn]);
      acc[1][1][fn] = mfma16(a[1], b1[fn][1], acc[1][1][fn]);
    }
    __builtin_amdgcn_s_setprio(0);
    if (st) asm volatile("s_waitcnt vmcnt(3)" ::: "memory");
    asm volatile("s_barrier" ::: "memory");
  }

  #pragma unroll
  for (int qm = 0; qm < 2; ++qm) {
    #pragma unroll
    for (int qn = 0; qn < 2; ++qn) {
      #pragma unroll
      for (int fn = 0; fn < 4; ++fn) {
        const int col = tileN + qn * 128 + wc * 64 + fn * 16 + l15;
        const float bv = bias[col];
        #pragma unroll
        for (int r = 0; r < 4; ++r) {
          const int row = tileM + qm * 64 + wr * 16 + quad * 4 + r;
          const size_t idx = (size_t)row * NN + col;
          outF[idx] = acc[qm][qn][fn][r] + bv + resid[idx];
        }
      }
    }
  }
}

// ---------------- MFMA flash attention v8 (+T5 setprio) -----------------
// 4 waves x 32 q-rows, grid 1024, 32KB LDS -> 4 blocks/CU. Swapped QK^T
// (S^T) -> P repack fully in-register. setprio around MFMA clusters:
// 4 independent blocks/CU at different kt phases = m191 regime.
__global__ __launch_bounds__(256, 4) void attn_mfma(const unsigned short* __restrict__ qB,
                                                    const unsigned short* __restrict__ kB,
                                                    const unsigned short* __restrict__ vtB,
                                                    unsigned short* __restrict__ aout) {
  __shared__ unsigned short Ks[2][64 * 64];
  __shared__ unsigned short Vs[2][64 * 64];

  const int tid = threadIdx.x;
  const int bid = blockIdx.x;
  const int bh = bid & 63;
  const int qb = bid >> 6;
  const int b = bh >> 4, h = bh & 15;
  const int wv = tid >> 6, lane = tid & 63;
  const int l15 = lane & 15, quad = lane >> 4;

  const unsigned short* qP = qB  + (size_t)bh * T_ * 64;
  const unsigned short* kP = kB  + (size_t)bh * T_ * 64;
  const unsigned short* vP = vtB + (size_t)bh * 64 * T_;
  const int q0 = qb * 128 + wv * 32;

  short8 qf[2][2];
  #pragma unroll
  for (int mi = 0; mi < 2; ++mi)
    #pragma unroll
    for (int ks = 0; ks < 2; ++ks)
      qf[mi][ks] = *(const short8*)(qP + ((size_t)(q0 + mi * 16 + l15)) * 64 + ks * 32 + quad * 8);

  const short8 onesf = {0x3F80, 0x3F80, 0x3F80, 0x3F80, 0x3F80, 0x3F80, 0x3F80, 0x3F80};
  f32x4 accO[2][5] = {};

  const int lrow  = lane >> 3;
  const int lchnk = (lane & 7) ^ (lrow & 7);
  const size_t kOff0 = (size_t)((wv * 2 + 0) * 8 + lrow) * 64 + lchnk * 8;
  const size_t kOff1 = (size_t)((wv * 2 + 1) * 8 + lrow) * 64 + lchnk * 8;
  const size_t vOff0 = (size_t)((wv * 2 + 0) * 8 + lrow) * T_ + lchnk * 8;
  const size_t vOff1 = (size_t)((wv * 2 + 1) * 8 + lrow) * T_ + lchnk * 8;
  const int lOff0 = (wv * 2 + 0) * 512 + lane * 8;
  const int lOff1 = (wv * 2 + 1) * 512 + lane * 8;

  async_cp16(kP + kOff0, &Ks[0][lOff0]);
  async_cp16(kP + kOff1, &Ks[0][lOff1]);
  async_cp16(vP + vOff0, &Vs[0][lOff0]);
  async_cp16(vP + vOff1, &Vs[0][lOff1]);
  __syncthreads();

  for (int kt = 0; kt < 32; ++kt) {
    const int buf = kt & 1;
    if (kt + 1 < 32) {
      const unsigned short* kg = kP + (size_t)(kt + 1) * 64 * 64;
      const unsigned short* vg = vP + (kt + 1) * 64;
      async_cp16(kg + kOff0, &Ks[buf ^ 1][lOff0]);
      async_cp16(kg + kOff1, &Ks[buf ^ 1][lOff1]);
      async_cp16(vg + vOff0, &Vs[buf ^ 1][lOff0]);
      async_cp16(vg + vOff1, &Vs[buf ^ 1][lOff1]);
    }
    const unsigned short* K_ = Ks[buf];
    const unsigned short* V_ = Vs[buf];

    f32x4 accT[4][2] = {};
    __builtin_amdgcn_s_setprio(1);
    #pragma unroll
    for (int ks = 0; ks < 2; ++ks) {
      #pragma unroll
      for (int cc = 0; cc < 4; ++cc) {
        const short8 kb = *(const short8*)&K_[(cc * 16 + l15) * 64 +
                                              (((ks << 2) | quad) ^ (l15 & 7)) * 8];
        accT[cc][0] = mfma16(kb, qf[0][ks], accT[cc][0]);
        accT[cc][1] = mfma16(kb, qf[1][ks], accT[cc][1]);
      }
    }
    __builtin_amdgcn_s_setprio(0);

    short8 pa[2][2];
    #pragma unroll
    for (int mi = 0; mi < 2; ++mi) {
      #pragma unroll
      for (int ks = 0; ks < 2; ++ks) {
        union { unsigned short u[8]; short8 s; } pk;
        #pragma unroll
        for (int r = 0; r < 4; ++r) {
          union { float f; unsigned int u; } e0, e1;
          e0.f = __builtin_amdgcn_exp2f(accT[2 * ks + 0][mi][r]);
          e1.f = __builtin_amdgcn_exp2f(accT[2 * ks + 1][mi][r]);
          pk.u[r]     = (unsigned short)(e0.u >> 16);
          pk.u[4 + r] = (unsigned short)(e1.u >> 16);
        }
        pa[mi][ks] = pk.s;
      }
    }

    __builtin_amdgcn_s_setprio(1);
    #pragma unroll
    for (int ks = 0; ks < 2; ++ks) {
      short8 vb[4];
      #pragma unroll
      for (int nj = 0; nj < 4; ++nj)
        vb[nj] = *(const short8*)&V_[(nj * 16 + l15) * 64 +
                                     (((ks << 2) | quad) ^ (l15 & 7)) * 8];
      #pragma unroll
      for (int mi = 0; mi < 2; ++mi) {
        #pragma unroll
        for (int nj = 0; nj < 4; ++nj)
          accO[mi][nj] = mfma16(pa[mi][ks], vb[nj], accO[mi][nj]);
        accO[mi][4] = mfma16(pa[mi][ks], onesf, accO[mi][4]);
      }
    }
    __builtin_amdgcn_s_setprio(0);

    __syncthreads();
  }

  #pragma unroll
  for (int mi = 0; mi < 2; ++mi) {
    #pragma unroll
    for (int r = 0; r < 4; ++r) {
      const float inv = 1.0f / accO[mi][4][r];
      const int row = q0 + mi * 16 + quad * 4 + r;
      unsigned short* op = aout + (size_t)(b * T_ + row) * D_ + h * 64 + l15;
      #pragma unroll
      for (int nj = 0; nj < 4; ++nj)
        op[nj * 16] = f2b16(accO[mi][nj][r] * inv);
    }
  }
}

extern "C" void kernel_launch(void* const* d_in, const int* in_sizes, int n_in,
                              void* d_out, int out_size, void* d_ws, size_t ws_size,
                              hipStream_t stream) {
  const float* x      = (const float*)d_in[0];
  const float* w_qkv  = (const float*)d_in[1];
  const float* b_qkv  = (const float*)d_in[2];
  const float* w_proj = (const float*)d_in[3];
  const float* b_proj = (const float*)d_in[4];
  const float* ln_g   = (const float*)d_in[5];
  const float* ln_b   = (const float*)d_in[6];
  float* out = (float*)d_out;

  char* ws = (char*)d_ws;
  unsigned short* xn   = (unsigned short*)(ws);                       // 16 MB (reused as aout)
  unsigned short* wTq  = (unsigned short*)(ws + (size_t)(16 << 20));  //  6 MB
  unsigned short* wTp  = (unsigned short*)(ws + (size_t)(22 << 20));  //  2 MB
  unsigned short* qBuf = (unsigned short*)(ws + (size_t)(24 << 20));  // 16 MB
  unsigned short* kBuf = (unsigned short*)(ws + (size_t)(40 << 20));  // 16 MB
  unsigned short* vtB  = (unsigned short*)(ws + (size_t)(72 << 20));  // 16 MB
  unsigned short* aout = xn;   // xn is dead after QKV gemm; attn reuses it

  // 1. fused prep: LN + both weight transposes (one dispatch)
  prep_kernel<<<12288, 256, 0, stream>>>(x, ln_g, ln_b, xn, w_qkv, wTq, w_proj, wTp);
  // 2. QKV projection (256^2 8-phase, 1 block/CU) with fused V-transpose
  gemm256_qkv<<<384, 512, 0, stream>>>(xn, wTq, b_qkv, qBuf, kBuf, vtB);
  // 3. MFMA flash attention v8 (+setprio)
  attn_mfma<<<1024, 256, 0, stream>>>(qBuf, kBuf, vtB, aout);
  // 4. output projection + bias + residual, fp32 out
  gemm8p<1, 1024><<<256, 512, 0, stream>>>(aout, wTp, b_proj, x, out);
}

// Round 8
// 256.597 us; speedup vs baseline: 2.6655x; 1.0439x over previous
//
#include <hip/hip_runtime.h>
#include <cstdint>
#include <cstddef>

#define B_ 4
#define T_ 2048
#define D_ 1024
#define H_ 16

typedef __attribute__((ext_vector_type(8))) short short8;     // 8 bf16 (4 VGPRs) for MFMA A/B frags
typedef __attribute__((ext_vector_type(4))) float f32x4;      // MFMA C/D frag
typedef __attribute__((ext_vector_type(8))) unsigned short u16x8;

__device__ __forceinline__ unsigned short f2b16(float f) {
  union { float f; unsigned int u; } un; un.f = f;
  unsigned int r = un.u + 0x7fffu + ((un.u >> 16) & 1u);  // round-to-nearest-even
  return (unsigned short)(r >> 16);
}
__device__ __forceinline__ void async_cp16(const void* g, void* l) {
  __builtin_amdgcn_global_load_lds((const __attribute__((address_space(1))) void*)g,
                                   (__attribute__((address_space(3))) void*)l,
                                   16, 0, 0);
}
__device__ __forceinline__ f32x4 mfma16(short8 a, short8 b, f32x4 c) {
  return __builtin_amdgcn_mfma_f32_16x16x32_bf16(a, b, c, 0, 0, 0);
}

// ====== prep: fused LayerNorm + transpose_cast(w_qkv) + transpose_cast(w_proj)
__global__ __launch_bounds__(256) void prep_kernel(const float* __restrict__ x,
                                                   const float* __restrict__ gamma,
                                                   const float* __restrict__ beta,
                                                   unsigned short* __restrict__ xn,
                                                   const float* __restrict__ wq,
                                                   unsigned short* __restrict__ wTq,
                                                   const float* __restrict__ wp,
                                                   unsigned short* __restrict__ wTp) {
  __shared__ float sh[8];
  __shared__ float tile[32][33];
  const int bid = blockIdx.x;
  const int t = threadIdx.x;

  if (bid < 8192) {
    // ---- LayerNorm ----
    const int row = bid;
    const float4 v = ((const float4*)(x + (size_t)row * D_))[t];
    float s  = v.x + v.y + v.z + v.w;
    float s2 = v.x*v.x + v.y*v.y + v.z*v.z + v.w*v.w;
    #pragma unroll
    for (int off = 32; off > 0; off >>= 1) {
      s  += __shfl_down(s, off);
      s2 += __shfl_down(s2, off);
    }
    const int wv = t >> 6, lane = t & 63;
    if (lane == 0) { sh[wv] = s; sh[4 + wv] = s2; }
    __syncthreads();
    if (t == 0) {
      float ts  = sh[0] + sh[1] + sh[2] + sh[3];
      float ts2 = sh[4] + sh[5] + sh[6] + sh[7];
      float mu  = ts * (1.0f / D_);
      float var = ts2 * (1.0f / D_) - mu * mu;
      sh[0] = mu;
      sh[1] = rsqrtf(var + 1e-5f);
    }
    __syncthreads();
    const float mu = sh[0], rs = sh[1];
    const float4 g  = ((const float4*)gamma)[t];
    const float4 bb = ((const float4*)beta)[t];
    ushort4 o;
    o.x = f2b16((v.x - mu) * rs * g.x + bb.x);
    o.y = f2b16((v.y - mu) * rs * g.y + bb.y);
    o.z = f2b16((v.z - mu) * rs * g.z + bb.z);
    o.w = f2b16((v.w - mu) * rs * g.w + bb.w);
    ((ushort4*)(xn + (size_t)row * D_))[t] = o;
  } else {
    // ---- transpose + cast ----
    const float* w; unsigned short* wT; int K, N, bx, by;
    if (bid < 8192 + 3072) {
      const int idx = bid - 8192;
      w = wq; wT = wTq; K = 1024; N = 3072; bx = idx % 96; by = idx / 96;
    } else {
      const int idx = bid - 11264;
      w = wp; wT = wTp; K = 1024; N = 1024; bx = idx % 32; by = idx / 32;
    }
    const int n0 = bx * 32, k0 = by * 32;
    const int tx = t & 31, ty = t >> 5;
    #pragma unroll
    for (int i = 0; i < 32; i += 8)
      tile[ty + i][tx] = w[(size_t)(k0 + ty + i) * N + n0 + tx];
    __syncthreads();
    #pragma unroll
    for (int i = 0; i < 32; i += 8)
      wT[(size_t)(n0 + ty + i) * K + k0 + tx] = f2b16(tile[tx][ty + i]);
  }
}

// ============ 256x256 8-phase QKV GEMM (proven R1/R2/R4 schedule) =======
// BM=BN=256, BK=64, 512 threads = 8 waves. Per-phase 16 MFMA, counted
// vmcnt fences (4/4/-/4), 1 barrier/phase. Grid 384.
// launch_bounds(512,2): 256-VGPR cap REQUIRED (R5: (512,4) spilled acc).
// XCD swizzle: M-CONTIGUOUS per XCD — xcd owns 4 M-tiles x 12 N,
// N-outer/M-inner order keeps the B-panel hot across its 4 uses.
// A-footprint/XCD = 2 MB < 4 MB L2 (R6 M-fast swizzle: FETCH 103 MB).
__global__ __launch_bounds__(512, 2) void gemm256_qkv(const unsigned short* __restrict__ A,
                                                      const unsigned short* __restrict__ Bt,
                                                      const float* __restrict__ bias,
                                                      unsigned short* __restrict__ qB,
                                                      unsigned short* __restrict__ kB,
                                                      unsigned short* __restrict__ vtB) {
  constexpr int K = 1024;
  constexpr int NT = K / 64;            // 16 K-tiles
  __shared__ __align__(16) unsigned short As[32768];   // 64KB: [buf][half][128][64]
  __shared__ __align__(16) unsigned short Bs[32768];   // 64KB

  const int tid  = threadIdx.x;
  const int lane = tid & 63;
  const int wv   = tid >> 6;            // 0..7
  const int l15  = lane & 15, quad = lane >> 4;
  const int wr   = wv >> 1;             // 0..3  (32-row slice within each qm-half)
  const int wc   = wv & 1;              // 0..1  (64-col slice within each qn-half)

  // XCD swizzle: xcd = bid&7 owns M-tiles [xcd*4, xcd*4+4) x all 12 N-tiles;
  // i = bid>>3 in 0..47, i&3 = M (fast), i>>2 = N (slow) -> B-panel reuse x4.
  const int xcd = blockIdx.x & 7;
  const int i   = blockIdx.x >> 3;
  const int tileM = (xcd * 4 + (i & 3)) * 256;
  const int tileN = (i >> 2) * 256;

  const int sr  = tid >> 3;
  const int scs = ((tid & 7) ^ (sr & 7)) * 8;
  const unsigned short* gA = A  + (size_t)(tileM + sr) * K + scs;
  const unsigned short* gB = Bt + (size_t)(tileN + sr) * K + scs;

  auto stageA = [&](int h, int ko, int wbuf) {
    const unsigned short* g = gA + (size_t)(h * 128) * K + ko;
    unsigned short* l = &As[wbuf * 16384 + h * 8192 + tid * 8];
    async_cp16(g, l);
    async_cp16(g + (size_t)64 * K, l + 4096);
  };
  auto stageB = [&](int h, int ko, int wbuf) {
    const unsigned short* g = gB + (size_t)(h * 128) * K + ko;
    unsigned short* l = &Bs[wbuf * 16384 + h * 8192 + tid * 8];
    async_cp16(g, l);
    async_cp16(g + (size_t)64 * K, l + 4096);
  };

  const int rA  = wr * 32 + l15;
  const int rB  = wc * 64 + l15;
  const int ck0 = ((0 + quad) ^ (l15 & 7)) * 8;
  const int ck1 = ((4 + quad) ^ (l15 & 7)) * 8;

  f32x4 acc[2][2][2][4] = {};                     // [qm][qn][fm][fn]

#define MFMA16(QM, QN, AF, BF)                                                          \
  do {                                                                                  \
    _Pragma("unroll") for (int fm = 0; fm < 2; ++fm)                                    \
    _Pragma("unroll") for (int fn = 0; fn < 4; ++fn) {                                  \
      acc[QM][QN][fm][fn] = mfma16(AF[fm][0], BF[fn][0], acc[QM][QN][fm][fn]);          \
      acc[QM][QN][fm][fn] = mfma16(AF[fm][1], BF[fn][1], acc[QM][QN][fm][fn]);          \
    }                                                                                   \
  } while (0)

  stageA(0, 0, 0);
  stageB(0, 0, 0);
  stageB(1, 0, 0);
  stageA(1, 0, 0);
  asm volatile("s_waitcnt vmcnt(4)" ::: "memory");
  asm volatile("s_barrier" ::: "memory");

  #pragma unroll 2
  for (int kt = 0; kt < NT; ++kt) {
    const int buf = kt & 1;
    const unsigned short* Ab = &As[buf * 16384];
    const unsigned short* Bb = &Bs[buf * 16384];
    const int wbuf = buf ^ 1;
    const bool st = (kt + 1) < NT;
    const int ko = (kt + 1) * 64;

    short8 a[2][2], b0[4][2], b1[4][2];

    // ---- phase 0: quadrant (0,0); reads A-half0 + B-half0
    #pragma unroll
    for (int fm = 0; fm < 2; ++fm) {
      a[fm][0] = *(const short8*)&Ab[(rA + fm * 16) * 64 + ck0];
      a[fm][1] = *(const short8*)&Ab[(rA + fm * 16) * 64 + ck1];
    }
    #pragma unroll
    for (int fn = 0; fn < 4; ++fn) {
      b0[fn][0] = *(const short8*)&Bb[(rB + fn * 16) * 64 + ck0];
      b0[fn][1] = *(const short8*)&Bb[(rB + fn * 16) * 64 + ck1];
    }
    if (st) stageA(0, ko, wbuf);
    asm volatile("s_waitcnt lgkmcnt(0)" ::: "memory");
    __builtin_amdgcn_sched_barrier(0);
    __builtin_amdgcn_s_setprio(1);
    MFMA16(0, 0, a, b0);
    __builtin_amdgcn_s_setprio(0);
    if (st) asm volatile("s_waitcnt vmcnt(4)" ::: "memory");   // force Bh1(kt)
    else    asm volatile("s_waitcnt vmcnt(2)" ::: "memory");
    asm volatile("s_barrier" ::: "memory");

    // ---- phase 1: quadrant (0,1); reads B-half1
    #pragma unroll
    for (int fn = 0; fn < 4; ++fn) {
      b1[fn][0] = *(const short8*)&Bb[8192 + (rB + fn * 16) * 64 + ck0];
      b1[fn][1] = *(const short8*)&Bb[8192 + (rB + fn * 16) * 64 + ck1];
    }
    if (st) stageB(0, ko, wbuf);
    asm volatile("s_waitcnt lgkmcnt(0)" ::: "memory");
    __builtin_amdgcn_sched_barrier(0);
    __builtin_amdgcn_s_setprio(1);
    MFMA16(0, 1, a, b1);
    __builtin_amdgcn_s_setprio(0);
    if (st) asm volatile("s_waitcnt vmcnt(4)" ::: "memory");   // force Ah1(kt)
    else    asm volatile("s_waitcnt vmcnt(0)" ::: "memory");
    asm volatile("s_barrier" ::: "memory");

    // ---- phase 2: quadrant (1,0); reads A-half1
    #pragma unroll
    for (int fm = 0; fm < 2; ++fm) {
      a[fm][0] = *(const short8*)&Ab[8192 + (rA + fm * 16) * 64 + ck0];
      a[fm][1] = *(const short8*)&Ab[8192 + (rA + fm * 16) * 64 + ck1];
    }
    if (st) stageB(1, ko, wbuf);
    asm volatile("s_waitcnt lgkmcnt(0)" ::: "memory");
    __builtin_amdgcn_sched_barrier(0);
    __builtin_amdgcn_s_setprio(1);
    MFMA16(1, 0, a, b0);
    __builtin_amdgcn_s_setprio(0);
    asm volatile("s_barrier" ::: "memory");

    // ---- phase 3: quadrant (1,1); no ds_reads
    if (st) stageA(1, ko, wbuf);
    __builtin_amdgcn_s_setprio(1);
    MFMA16(1, 1, a, b1);
    __builtin_amdgcn_s_setprio(0);
    if (st) asm volatile("s_waitcnt vmcnt(4)" ::: "memory");   // force Ah0+Bh0(kt+1)
    asm volatile("s_barrier" ::: "memory");
  }
#undef MFMA16

  if (tileN < 2048) {
    // ---- Q/K epilogue: per-wave LDS restage -> coalesced b128 stores
    unsigned short* E = &As[wv * 2304];   // 32 x 72, wave-local
    #pragma unroll
    for (int qm = 0; qm < 2; ++qm) {
      #pragma unroll
      for (int qn = 0; qn < 2; ++qn) {
        const int colBase = tileN + qn * 128 + wc * 64;
        const int rowBase = tileM + qm * 128 + wr * 32;
        #pragma unroll
        for (int fn = 0; fn < 4; ++fn) {
          const int col = colBase + fn * 16 + l15;
          const float bv = bias[col];
          const float sc = (col < 1024) ? 0.180336880f : 1.0f;  // Q: fold 0.125*log2e
          #pragma unroll
          for (int fm = 0; fm < 2; ++fm)
            #pragma unroll
            for (int r = 0; r < 4; ++r)
              E[(fm * 16 + quad * 4 + r) * 72 + fn * 16 + l15] =
                  f2b16((acc[qm][qn][fm][fn][r] + bv) * sc);
        }
        const int secq = colBase >> 10;                    // 0=Q, 1=K
        const int hh   = (colBase & 1023) >> 6;
        unsigned short* outSec = (secq == 0) ? qB : kB;
        #pragma unroll
        for (int it = 0; it < 4; ++it) {
          const int lrow = it * 8 + (lane >> 3);
          const int row = rowBase + lrow;
          const int b_ = row >> 11, tt = row & 2047;
          const u16x8 val = *(const u16x8*)&E[lrow * 72 + (lane & 7) * 8];
          *(u16x8*)(outSec + ((size_t)(b_ * 16 + hh) * T_ + tt) * 64 + (lane & 7) * 8) = val;
        }
      }
    }
  } else {
    // ---- V epilogue: fused transpose -> vtB[bh][dv][t'] (c' permuted).
    const int b_    = tileM >> 11;
    const int tbase = tileM & 2047;
    const int h0    = (tileN - 2048) >> 6;
    unsigned short* TL = (wr < 2) ? As : Bs;  // write-side tile array
    const int cpr = 32 * (wr & 1) + 8 * quad;
    #pragma unroll
    for (int qm = 0; qm < 2; ++qm) {
      #pragma unroll
      for (int qn = 0; qn < 2; ++qn) {
        const int head = qn * 2 + wc;
        const int colBase = tileN + qn * 128 + wc * 64;
        #pragma unroll
        for (int fn = 0; fn < 4; ++fn) {
          const int dv = fn * 16 + l15;
          const float bv = bias[colBase + fn * 16 + l15];
          #pragma unroll
          for (int fm = 0; fm < 2; ++fm)
            #pragma unroll
            for (int r = 0; r < 4; ++r)
              TL[head * 4352 + dv * 68 + cpr + 4 * fm + r] =
                  f2b16(acc[qm][qn][fm][fn][r] + bv);
        }
      }
      __syncthreads();
      {
        const unsigned short* SA = (wv < 4) ? As : Bs;
        const int head = wv & 3;
        const int tb   = qm * 2 + (wv >> 2);
        const size_t base = ((size_t)(b_ * 16 + h0 + head) * 64) * T_ + tbase + tb * 64;
        const int c4 = (lane & 15) * 4;
        #pragma unroll
        for (int i2 = 0; i2 < 16; ++i2) {
          const int dv = i2 * 4 + (lane >> 4);
          const ushort4 val = *(const ushort4*)&SA[head * 4352 + dv * 68 + c4];
          *(ushort4*)(vtB + base + (size_t)dv * T_ + c4) = val;
        }
      }
      __syncthreads();
    }
  }
}

// ------ 128x256 8-phase GEMM (output projection, fp32 + bias + resid) ---
template <int MODE, int NN>
__global__ __launch_bounds__(512, 2) void gemm8p(const unsigned short* __restrict__ A,
                                                 const unsigned short* __restrict__ Bt,
                                                 const float* __restrict__ bias,
                                                 const float* __restrict__ resid,
                                                 float* __restrict__ outF) {
  constexpr int K = 1024;
  constexpr int NT = 16;
  __shared__ __align__(16) unsigned short As[16384];
  __shared__ __align__(16) unsigned short Bs[32768];

  const int tid  = threadIdx.x;
  const int lane = tid & 63;
  const int wv   = tid >> 6;
  const int l15  = lane & 15, quad = lane >> 4;
  const int wr   = wv >> 1;
  const int wc   = wv & 1;

  constexpr int CPX = (64 * (NN / 256)) / 8;
  const int w = (blockIdx.x & 7) * CPX + (blockIdx.x >> 3);
  const int tileM = (w & 63) * 128;
  const int tileN = (w >> 6) * 256;

  const int sr  = tid >> 3;
  const int scs = ((tid & 7) ^ (sr & 7)) * 8;
  const unsigned short* gA = A  + (size_t)(tileM + sr) * K + scs;
  const unsigned short* gB = Bt + (size_t)(tileN + sr) * K + scs;

  auto stA = [&](int h, int ko, int wb) {
    async_cp16(gA + (size_t)(h * 64) * K + ko, &As[wb * 8192 + h * 4096 + tid * 8]);
  };
  auto stB = [&](int h, int ko, int wb) {
    const unsigned short* g = gB + (size_t)(h * 128) * K + ko;
    unsigned short* l = &Bs[wb * 16384 + h * 8192 + tid * 8];
    async_cp16(g, l);
    async_cp16(g + (size_t)64 * K, l + 4096);
  };

  const int rA  = wr * 16 + l15;
  const int rB  = wc * 64 + l15;
  const int ck0 = ((0 + quad) ^ (l15 & 7)) * 8;
  const int ck1 = ((4 + quad) ^ (l15 & 7)) * 8;

  f32x4 acc[2][2][4] = {};

  stA(0, 0, 0); stB(0, 0, 0); stB(1, 0, 0); stA(1, 0, 0);
  asm volatile("s_waitcnt vmcnt(3)" ::: "memory");
  asm volatile("s_barrier" ::: "memory");

  #pragma unroll 2
  for (int kt = 0; kt < NT; ++kt) {
    const int buf = kt & 1;
    const unsigned short* Ab = &As[buf * 8192];
    const unsigned short* Bb = &Bs[buf * 16384];
    const int wb = buf ^ 1;
    const bool st = (kt + 1) < NT;
    const int ko = (kt + 1) * 64;

    short8 a[2], b0[4][2], b1[4][2];

    a[0] = *(const short8*)&Ab[rA * 64 + ck0];
    a[1] = *(const short8*)&Ab[rA * 64 + ck1];
    #pragma unroll
    for (int fn = 0; fn < 4; ++fn) {
      b0[fn][0] = *(const short8*)&Bb[(rB + fn * 16) * 64 + ck0];
      b0[fn][1] = *(const short8*)&Bb[(rB + fn * 16) * 64 + ck1];
    }
    if (st) stA(0, ko, wb);
    asm volatile("s_waitcnt lgkmcnt(0)" ::: "memory");
    __builtin_amdgcn_sched_barrier(0);
    __builtin_amdgcn_s_setprio(1);
    #pragma unroll
    for (int fn = 0; fn < 4; ++fn) {
      acc[0][0][fn] = mfma16(a[0], b0[fn][0], acc[0][0][fn]);
      acc[0][0][fn] = mfma16(a[1], b0[fn][1], acc[0][0][fn]);
    }
    __builtin_amdgcn_s_setprio(0);
    if (st) asm volatile("s_waitcnt vmcnt(2)" ::: "memory");
    else    asm volatile("s_waitcnt vmcnt(1)" ::: "memory");
    asm volatile("s_barrier" ::: "memory");

    #pragma unroll
    for (int fn = 0; fn < 4; ++fn) {
      b1[fn][0] = *(const short8*)&Bb[8192 + (rB + fn * 16) * 64 + ck0];
      b1[fn][1] = *(const short8*)&Bb[8192 + (rB + fn * 16) * 64 + ck1];
    }
    if (st) stB(0, ko, wb);
    asm volatile("s_waitcnt lgkmcnt(0)" ::: "memory");
    __builtin_amdgcn_sched_barrier(0);
    __builtin_amdgcn_s_setprio(1);
    #pragma unroll
    for (int fn = 0; fn < 4; ++fn) {
      acc[0][1][fn] = mfma16(a[0], b1[fn][0], acc[0][1][fn]);
      acc[0][1][fn] = mfma16(a[1], b1[fn][1], acc[0][1][fn]);
    }
    __builtin_amdgcn_s_setprio(0);
    if (st) asm volatile("s_waitcnt vmcnt(3)" ::: "memory");
    else    asm volatile("s_waitcnt vmcnt(0)" ::: "memory");
    asm volatile("s_barrier" ::: "memory");

    a[0] = *(const short8*)&Ab[4096 + rA * 64 + ck0];
    a[1] = *(const short8*)&Ab[4096 + rA * 64 + ck1];
    if (st) stB(1, ko, wb);
    asm volatile("s_waitcnt lgkmcnt(0)" ::: "memory");
    __builtin_amdgcn_sched_barrier(0);
    __builtin_amdgcn_s_setprio(1);
    #pragma unroll
    for (int fn = 0; fn < 4; ++fn) {
      acc[1][0][fn] = mfma16(a[0], b0[fn][0], acc[1][0][fn]);
      acc[1][0][fn] = mfma16(a[1], b0[fn][1], acc[1][0][fn]);
    }
    __builtin_amdgcn_s_setprio(0);
    asm volatile("s_barrier" ::: "memory");

    if (st) stA(1, ko, wb);
    __builtin_amdgcn_s_setprio(1);
    #pragma unroll
    for (int fn = 0; fn < 4; ++fn) {
      acc[1][1][fn] = mfma16(a[0], b1[fn][0], acc[1][1][fn]);
      acc[1][1][fn] = mfma16(a[1], b1[fn][1], acc[1][1][fn]);
    }
    __builtin_amdgcn_s_setprio(0);
    if (st) asm volatile("s_waitcnt vmcnt(3)" ::: "memory");
    asm volatile("s_barrier" ::: "memory");
  }

  #pragma unroll
  for (int qm = 0; qm < 2; ++qm) {
    #pragma unroll
    for (int qn = 0; qn < 2; ++qn) {
      #pragma unroll
      for (int fn = 0; fn < 4; ++fn) {
        const int col = tileN + qn * 128 + wc * 64 + fn * 16 + l15;
        const float bv = bias[col];
        #pragma unroll
        for (int r = 0; r < 4; ++r) {
          const int row = tileM + qm * 64 + wr * 16 + quad * 4 + r;
          const size_t idx = (size_t)row * NN + col;
          outF[idx] = acc[qm][qn][fn][r] + bv + resid[idx];
        }
      }
    }
  }
}

// ---------------- MFMA flash attention v9: pipelined -------------------
// Software pipeline: per iteration kt, {DMA K(kt+2),V(kt+1)} || QK^T(kt+1)
// [MFMA] -> PV(kt) [MFMA] -> pack(kt+1) [VALU, overlaps PV pipe time].
// R6 counters proved the pipes were serialized (MfmaUtil 43 + VALUBusy 45,
// makespan = sum): the in-tile QKT->exp->PV chain never anti-phased. K is
// TRIPLE-buffered (QK^T(kt+1) during kt), V stays double-buffered: LDS =
// 3*8K + 2*8K = 40 KB -> still exactly 4 blocks/CU (160 KB).
// Slot-lifetime audit (R8): DMA target kd was QKT source at kt-2 (2
// barriers back); V DMA target (kt+1)&1 was PV source at kt-1 (1 barrier
// back); every DMA drained by iter-end __syncthreads before its reader.
// Numerics identical: same MFMA operands/order per element as v8.
__global__ __launch_bounds__(256, 4) void attn_mfma(const unsigned short* __restrict__ qB,
                                                    const unsigned short* __restrict__ kB,
                                                    const unsigned short* __restrict__ vtB,
                                                    unsigned short* __restrict__ aout) {
  __shared__ unsigned short Ks[3 * 4096];   // swizzled K tiles, triple-buffered
  __shared__ unsigned short Vs[2 * 4096];   // swizzled V^T tiles, double-buffered

  const int tid = threadIdx.x;
  const int bid = blockIdx.x;
  const int bh = bid & 63;
  const int qb = bid >> 6;
  const int b = bh >> 4, h = bh & 15;
  const int wv = tid >> 6, lane = tid & 63;
  const int l15 = lane & 15, quad = lane >> 4;

  const unsigned short* qP = qB  + (size_t)bh * T_ * 64;
  const unsigned short* kP = kB  + (size_t)bh * T_ * 64;
  const unsigned short* vP = vtB + (size_t)bh * 64 * T_;
  const int q0 = qb * 128 + wv * 32;

  short8 qf[2][2];
  #pragma unroll
  for (int mi = 0; mi < 2; ++mi)
    #pragma unroll
    for (int ks = 0; ks < 2; ++ks)
      qf[mi][ks] = *(const short8*)(qP + ((size_t)(q0 + mi * 16 + l15)) * 64 + ks * 32 + quad * 8);

  const short8 onesf = {0x3F80, 0x3F80, 0x3F80, 0x3F80, 0x3F80, 0x3F80, 0x3F80, 0x3F80};
  f32x4 accO[2][5] = {};
  f32x4 accT[4][2];     // S^T accumulator for tile kt+1 (reused every iter)
  short8 pa[2][2];      // packed P for tile kt

  const int lrow  = lane >> 3;
  const int lchnk = (lane & 7) ^ (lrow & 7);
  const size_t kOff0 = (size_t)((wv * 2 + 0) * 8 + lrow) * 64 + lchnk * 8;
  const size_t kOff1 = (size_t)((wv * 2 + 1) * 8 + lrow) * 64 + lchnk * 8;
  const size_t vOff0 = (size_t)((wv * 2 + 0) * 8 + lrow) * T_ + lchnk * 8;
  const size_t vOff1 = (size_t)((wv * 2 + 1) * 8 + lrow) * T_ + lchnk * 8;
  const int lOff0 = (wv * 2 + 0) * 512 + lane * 8;
  const int lOff1 = (wv * 2 + 1) * 512 + lane * 8;

  // QK^T for one K-tile from LDS base K_ -> accT (zero-init inside)
  auto QKT = [&](const unsigned short* K_) {
    #pragma unroll
    for (int cc = 0; cc < 4; ++cc) {
      accT[cc][0] = f32x4{0.f, 0.f, 0.f, 0.f};
      accT[cc][1] = f32x4{0.f, 0.f, 0.f, 0.f};
    }
    #pragma unroll
    for (int ks = 0; ks < 2; ++ks) {
      #pragma unroll
      for (int cc = 0; cc < 4; ++cc) {
        const short8 kb = *(const short8*)&K_[(cc * 16 + l15) * 64 +
                                              (((ks << 2) | quad) ^ (l15 & 7)) * 8];
        accT[cc][0] = mfma16(kb, qf[0][ks], accT[cc][0]);
        accT[cc][1] = mfma16(kb, qf[1][ks], accT[cc][1]);
      }
    }
  };
  // pack accT -> pa  (exp2, bf16 truncate, kv' register layout)
  auto PACK = [&]() {
    #pragma unroll
    for (int mi = 0; mi < 2; ++mi) {
      #pragma unroll
      for (int ks = 0; ks < 2; ++ks) {
        union { unsigned short u[8]; short8 s; } pk;
        #pragma unroll
        for (int r = 0; r < 4; ++r) {
          union { float f; unsigned int u; } e0, e1;
          e0.f = __builtin_amdgcn_exp2f(accT[2 * ks + 0][mi][r]);
          e1.f = __builtin_amdgcn_exp2f(accT[2 * ks + 1][mi][r]);
          pk.u[r]     = (unsigned short)(e0.u >> 16);
          pk.u[4 + r] = (unsigned short)(e1.u >> 16);
        }
        pa[mi][ks] = pk.s;
      }
    }
  };

  // prologue: DMA K0, V0, K1; then pre-compute pa(0)
  async_cp16(kP + kOff0, &Ks[lOff0]);
  async_cp16(kP + kOff1, &Ks[lOff1]);
  async_cp16(vP + vOff0, &Vs[lOff0]);
  async_cp16(vP + vOff1, &Vs[lOff1]);
  async_cp16(kP + 4096 + kOff0, &Ks[4096 + lOff0]);
  async_cp16(kP + 4096 + kOff1, &Ks[4096 + lOff1]);
  __syncthreads();              // K0, V0, K1 visible
  QKT(&Ks[0]);
  PACK();                       // pa(0)

  int kq = 1;                   // K-slot holding tile kt+1
  int kd = 2;                   // K-slot to DMA tile kt+2 into
  for (int kt = 0; kt < 32; ++kt) {
    // DMA next tiles (slot kd's previous occupant was last read 2 barriers ago)
    if (kt < 30) {
      const unsigned short* kg = kP + (size_t)(kt + 2) * 4096;
      async_cp16(kg + kOff0, &Ks[kd * 4096 + lOff0]);
      async_cp16(kg + kOff1, &Ks[kd * 4096 + lOff1]);
    }
    if (kt < 31) {
      const unsigned short* vg = vP + (kt + 1) * 64;
      async_cp16(vg + vOff0, &Vs[((kt + 1) & 1) * 4096 + lOff0]);
      async_cp16(vg + vOff1, &Vs[((kt + 1) & 1) * 4096 + lOff1]);
    }
    const unsigned short* V_ = &Vs[(kt & 1) * 4096];

    __builtin_amdgcn_s_setprio(1);
    if (kt < 31) QKT(&Ks[kq * 4096]);     // accT for tile kt+1 (MFMA)

    // PV(kt): accO += pa(kt) @ V'(kt); nj=4 = ones (l sum)  (MFMA)
    #pragma unroll
    for (int ks = 0; ks < 2; ++ks) {
      short8 vb[4];
      #pragma unroll
      for (int nj = 0; nj < 4; ++nj)
        vb[nj] = *(const short8*)&V_[(nj * 16 + l15) * 64 +
                                     (((ks << 2) | quad) ^ (l15 & 7)) * 8];
      #pragma unroll
      for (int mi = 0; mi < 2; ++mi) {
        #pragma unroll
        for (int nj = 0; nj < 4; ++nj)
          accO[mi][nj] = mfma16(pa[mi][ks], vb[nj], accO[mi][nj]);
        accO[mi][4] = mfma16(pa[mi][ks], onesf, accO[mi][4]);
      }
    }
    __builtin_amdgcn_s_setprio(0);

    if (kt < 31) PACK();                  // pa(kt+1): VALU, executes under PV

    __syncthreads();                      // drains DMA; guards all buffers
    const int kn = 3 - kq - kd;           // slot of tile kt (just freed role)
    kq = kd;
    kd = kn;
  }

  // normalize by l and store bf16
  #pragma unroll
  for (int mi = 0; mi < 2; ++mi) {
    #pragma unroll
    for (int r = 0; r < 4; ++r) {
      const float inv = 1.0f / accO[mi][4][r];
      const int row = q0 + mi * 16 + quad * 4 + r;
      unsigned short* op = aout + (size_t)(b * T_ + row) * D_ + h * 64 + l15;
      #pragma unroll
      for (int nj = 0; nj < 4; ++nj)
        op[nj * 16] = f2b16(accO[mi][nj][r] * inv);
    }
  }
}

extern "C" void kernel_launch(void* const* d_in, const int* in_sizes, int n_in,
                              void* d_out, int out_size, void* d_ws, size_t ws_size,
                              hipStream_t stream) {
  const float* x      = (const float*)d_in[0];
  const float* w_qkv  = (const float*)d_in[1];
  const float* b_qkv  = (const float*)d_in[2];
  const float* w_proj = (const float*)d_in[3];
  const float* b_proj = (const float*)d_in[4];
  const float* ln_g   = (const float*)d_in[5];
  const float* ln_b   = (const float*)d_in[6];
  float* out = (float*)d_out;

  char* ws = (char*)d_ws;
  unsigned short* xn   = (unsigned short*)(ws);                       // 16 MB (reused as aout)
  unsigned short* wTq  = (unsigned short*)(ws + (size_t)(16 << 20));  //  6 MB
  unsigned short* wTp  = (unsigned short*)(ws + (size_t)(22 << 20));  //  2 MB
  unsigned short* qBuf = (unsigned short*)(ws + (size_t)(24 << 20));  // 16 MB
  unsigned short* kBuf = (unsigned short*)(ws + (size_t)(40 << 20));  // 16 MB
  unsigned short* vtB  = (unsigned short*)(ws + (size_t)(72 << 20));  // 16 MB
  unsigned short* aout = xn;   // xn is dead after QKV gemm; attn reuses it

  // 1. fused prep: LN + both weight transposes (one dispatch)
  prep_kernel<<<12288, 256, 0, stream>>>(x, ln_g, ln_b, xn, w_qkv, wTq, w_proj, wTp);
  // 2. QKV projection (256^2 8-phase, M-contiguous XCD swizzle) + fused V^T
  gemm256_qkv<<<384, 512, 0, stream>>>(xn, wTq, b_qkv, qBuf, kBuf, vtB);
  // 3. MFMA flash attention v9 (software-pipelined, K triple-buffered)
  attn_mfma<<<1024, 256, 0, stream>>>(qBuf, kBuf, vtB, aout);
  // 4. output projection + bias + residual, fp32 out
  gemm8p<1, 1024><<<256, 512, 0, stream>>>(aout, wTp, b_proj, x, out);
}